// Round 15
// baseline (325.451 us; speedup 1.0000x reference)
//
#include <hip/hip_runtime.h>
#include <hip/hip_bf16.h>
#include <cstddef>

#define H 200
#define NA 48
#define NBB 96
#define BATCH 128
#define AFD 39
#define BFD 50          // 39+11
#define LP 1000
#define CATD (AFD + H)  // 239
#define BIPB 16         // bonds per block in bond-input kernel
#define VOCAB 26
#define EROW 56         // padded bf16 emb row (50 -> 56 ushorts, 16B-aligned)

typedef unsigned short ushort_t;
typedef __bf16 bf16x8 __attribute__((ext_vector_type(8)));
typedef float f32x16 __attribute__((ext_vector_type(16)));
typedef unsigned uint32x4 __attribute__((ext_vector_type(4)));

union U16B { uint4 u; bf16x8 b; };
static __device__ __forceinline__ bf16x8 as_bf16x8(uint4 u) { U16B x; x.u = u; return x.b; }
union U16B2 { uint32x4 u; bf16x8 b; };
static __device__ __forceinline__ bf16x8 as_bf16x8v(uint32x4 u) { U16B2 x; x.u = u; return x.b; }

// float -> bf16 (RNE)
static __device__ __forceinline__ ushort_t f2bf(float f) {
    union { float f; unsigned u; } a; a.f = f;
    unsigned r = (a.u + 0x7FFFu + ((a.u >> 16) & 1u)) >> 16;
    return (ushort_t)r;
}

// raw asm global load: 16B at sgpr-base + 32-bit voffset. asm volatile pins issue
// order -> counted vmcnt discipline stays valid. "=&v" early-clobber.
static __device__ __forceinline__ uint32x4 gload16(const ushort_t* base, unsigned voff) {
    uint32x4 r;
    asm volatile("global_load_dwordx4 %0, %1, %2"
                 : "=&v"(r) : "v"(voff), "s"(base));
    return r;
}

// ---------------- prep: weight swizzles (32x32x16 A-frag order) ----------------
template <int COUT, int CIN, int CP, int K>
static __device__ __forceinline__ void prep_one(int t, const float* __restrict__ w,
                                                ushort_t* __restrict__ Wb) {
    constexpr int NC = CP / 16;
    constexpr int NS = K * NC;
    int j = t & 7;
    int lane = (t >> 3) & 63;
    int s = (t >> 9) % NS;
    int ct = (t >> 9) / NS;
    int co = ct * 32 + (lane & 31);
    int tt = s / NC, cc = s % NC;
    int ci = cc * 16 + ((lane >> 5) & 1) * 8 + j;
    float v = 0.f;
    if (co < COUT && ci < CIN) v = w[((size_t)co * CIN + ci) * K + tt];
    Wb[t] = f2bf(v);
}

#define MNS 13                            // K-steps for msg GEMM (208/16)
#define ANS 15                            // K-steps for atom GEMM (240/16)
#define PREP_T0 (4 * 12 * 512)            // conv0: 4 tiles x NS=12
#define PREP_T1 (PREP_T0 + 4 * 30 * 512)  // conv1: 4 tiles x NS=30
#define PREP_T2 (PREP_T1 + 8 * 56 * 512)  // conv2: 8 tiles x NS=56
#define PREP_T3 (PREP_T2 + 51200)         // zero x
#define PREP_T4 (PREP_T3 + 8 * MNS * 512) // Wh swizzle: 8 tiles x 13 steps
#define PREP_T5 (PREP_T4 + 8 * ANS * 512) // Wo swizzle (permuted K: nei|fa|pad)
#define PREP_T6 (PREP_T5 + VOCAB * EROW)  // emb -> bf16 padded table (2.8KB)
#define PREP_T7 (PREP_T6 + 200 * 400)     // fc0w transpose (coalesced reads)
#define PREP_T8 (PREP_T7 + 100 * 200)     // fc1w transpose
#define PREP_BLKS ((PREP_T8 + 255) / 256)

static __device__ __forceinline__ void prep_body(
        int tid, const float* __restrict__ c0w, const float* __restrict__ c1w,
        const float* __restrict__ c2w, const float* __restrict__ Wh,
        const float* __restrict__ Wo, const float* __restrict__ emb,
        const float* __restrict__ fc0w, const float* __restrict__ fc1w,
        float* __restrict__ x,
        ushort_t* __restrict__ Wb0, ushort_t* __restrict__ Wb1,
        ushort_t* __restrict__ Wb2, ushort_t* __restrict__ Wbh,
        ushort_t* __restrict__ Wbo, ushort_t* __restrict__ embb,
        float* __restrict__ w0t, float* __restrict__ w1t) {
    if (tid < PREP_T0) prep_one<96, 50, 64, 3>(tid, c0w, Wb0);
    else if (tid < PREP_T1) prep_one<128, 96, 96, 5>(tid - PREP_T0, c1w, Wb1);
    else if (tid < PREP_T2) prep_one<200, 128, 128, 7>(tid - PREP_T1, c2w, Wb2);
    else if (tid < PREP_T3) x[tid - PREP_T2] = 0.f;
    else if (tid < PREP_T4) {
        // Wh stored (in,out): value for (co, ci) = Wh[ci*200 + co]
        int t = tid - PREP_T3;
        int j = t & 7;
        int lane = (t >> 3) & 63;
        int s = (t >> 9) % MNS;
        int tile = (t >> 9) / MNS;
        int co = tile * 32 + (lane & 31);
        int ci = s * 16 + ((lane >> 5) & 1) * 8 + j;
        float v = 0.f;
        if (co < H && ci < H) v = Wh[ci * H + co];
        Wbh[t] = f2bf(v);
    } else if (tid < PREP_T5) {
        // Wo stored (in=239, out=200). Permuted K-axis ci' : [0,200)=nei -> Wo row 39+ci',
        // [200,239)=fa -> Wo row ci'-200, 239 = pad.
        int t = tid - PREP_T4;
        int j = t & 7;
        int lane = (t >> 3) & 63;
        int s = (t >> 9) % ANS;
        int tile = (t >> 9) / ANS;
        int co = tile * 32 + (lane & 31);
        int cip = s * 16 + ((lane >> 5) & 1) * 8 + j;
        float v = 0.f;
        if (co < H) {
            if (cip < 200) v = Wo[(size_t)(39 + cip) * H + co];
            else if (cip < CATD) v = Wo[(size_t)(cip - 200) * H + co];
        }
        Wbo[t] = f2bf(v);
    } else if (tid < PREP_T6) {
        // bf16 emb table, zero-padded 50->56 (conv0 staging: 7 uint4s per row)
        int t = tid - PREP_T5;
        int s = t / EROW, cc = t - s * EROW;
        embb[t] = (cc < 50) ? f2bf(emb[(size_t)s * 50 + cc]) : (ushort_t)0;
    } else if (tid < PREP_T7) {
        // consecutive tid -> consecutive READ addr (co fastest); scattered writes.
        int t = tid - PREP_T6;
        int co = t % 200, k = t / 200;
        w0t[(size_t)co * 400 + k] = fc0w[(size_t)k * 200 + co];
    } else if (tid < PREP_T8) {
        int t = tid - PREP_T7;
        int co = t % 100, k = t / 100;
        w1t[(size_t)co * 200 + k] = fc1w[(size_t)k * 100 + co];
    }
}

// ---------------- MFMA conv1d body, 32x32x16 ----------------
// R8 WIN: inline-asm A ring, counted s_waitcnt vmcnt + sched_barrier(0).
// R17: D back to 4 (R16's D=3 cost ~3us on conv2; occupancy unchanged -> register
// boundary theory falsified).
template <int CP, int K, int COUT, int CO_WAVES, int L_WAVES, bool FMAX, bool EMB>
static __device__ __forceinline__ void conv_body(
        const ushort_t* __restrict__ act, const int* __restrict__ seq,
        const ushort_t* __restrict__ embb, const ushort_t* __restrict__ Wb,
        const float* __restrict__ bias, void* __restrict__ outv,
        ushort_t* __restrict__ Xs, int bofs) {
    constexpr int NC = CP / 16;
    constexpr int NS = K * NC;
    constexpr int P = K / 2;
    constexpr int PITCH = CP + 8;
    constexpr int LTILE = 64 * L_WAVES;
    constexpr int ROWS = LTILE + K - 1;
    constexpr int CPR = CP / 8;
    constexpr int D = 4;

    int b = blockIdx.z + bofs, lb = blockIdx.x;
    int l0 = lb * LTILE;
    int tid = threadIdx.x;

    if (EMB) {
        const int* seqb = seq + (size_t)b * LP;
        for (int idx = tid; idx < ROWS * CPR; idx += 256) {
            int r = idx / CPR, c = idx % CPR;
            int l = l0 - P + r;
            uint4 v = {0u, 0u, 0u, 0u};
            if ((unsigned)l < (unsigned)LP && c < 7) {
                int s = seqb[l];
                v = *(const uint4*)(embb + (size_t)s * EROW + c * 8);
            }
            *(uint4*)(Xs + r * PITCH + c * 8) = v;
        }
    } else {
        const ushort_t* actb = act + (size_t)b * LP * CP;
        for (int idx = tid; idx < ROWS * CPR; idx += 256) {
            int r = idx / CPR, c = idx % CPR;
            int l = l0 - P + r;
            uint4 v = {0u, 0u, 0u, 0u};
            if ((unsigned)l < (unsigned)LP) v = *(const uint4*)(actb + (size_t)l * CP + c * 8);
            *(uint4*)(Xs + r * PITCH + c * 8) = v;
        }
    }

    int lane = tid & 63, wv = tid >> 6;
    int cw = wv % CO_WAVES, lw = wv / CO_WAVES;
    int ln31 = lane & 31, half = lane >> 5;

    unsigned abase0 = (unsigned)(cw * 2) * (unsigned)NS * 1024u + (unsigned)lane * 16u;
    unsigned abase1 = abase0 + (unsigned)NS * 1024u;
    int bbase = (lw * 64 + ln31) * PITCH + half * 8;

    f32x16 acc[2][2];
#pragma unroll
    for (int ct = 0; ct < 2; ++ct)
#pragma unroll
        for (int lt = 0; lt < 2; ++lt)
#pragma unroll
            for (int r = 0; r < 16; ++r) acc[ct][lt][r] = 0.f;

    __syncthreads();   // staging drained -> vmcnt counts ONLY ring loads

    uint32x4 ra0[D], ra1[D];
#pragma unroll
    for (int d = 0; d < D; ++d) {
        ra0[d] = gload16(Wb, abase0 + (unsigned)(d * 1024));
        ra1[d] = gload16(Wb, abase1 + (unsigned)(d * 1024));
    }

    uint4 bC0 = *(const uint4*)(Xs + bbase);
    uint4 bC1 = *(const uint4*)(Xs + bbase + 32 * PITCH);

#pragma unroll
    for (int s = 0; s < NS; ++s) {
        int sn = (s + 1 < NS) ? s + 1 : NS - 1;
        int tn = sn / NC, ccn = sn % NC;
        int off = bbase + tn * PITCH + ccn * 16;
        uint4 bN0 = *(const uint4*)(Xs + off);
        uint4 bN1 = *(const uint4*)(Xs + off + 32 * PITCH);

        {
            const int rem = NS - 1 - s;
            const int allow = 2 * ((D - 1) < rem ? (D - 1) : rem);
            asm volatile("s_waitcnt vmcnt(%0)" :: "i"(allow) : "memory");
            __builtin_amdgcn_sched_barrier(0);
        }

        uint32x4 a0 = ra0[s % D];
        uint32x4 a1 = ra1[s % D];

        acc[0][0] = __builtin_amdgcn_mfma_f32_32x32x16_bf16(
            as_bf16x8v(a0), as_bf16x8(bC0), acc[0][0], 0, 0, 0);
        acc[1][0] = __builtin_amdgcn_mfma_f32_32x32x16_bf16(
            as_bf16x8v(a1), as_bf16x8(bC0), acc[1][0], 0, 0, 0);
        acc[0][1] = __builtin_amdgcn_mfma_f32_32x32x16_bf16(
            as_bf16x8v(a0), as_bf16x8(bC1), acc[0][1], 0, 0, 0);
        acc[1][1] = __builtin_amdgcn_mfma_f32_32x32x16_bf16(
            as_bf16x8v(a1), as_bf16x8(bC1), acc[1][1], 0, 0, 0);

        if (s + D < NS) {
            ra0[s % D] = gload16(Wb, abase0 + (unsigned)((s + D) * 1024));
            ra1[s % D] = gload16(Wb, abase1 + (unsigned)((s + D) * 1024));
        }

        bC0 = bN0; bC1 = bN1;
    }

    if (!FMAX) {
        ushort_t* out = (ushort_t*)outv + (size_t)b * LP * COUT;
#pragma unroll
        for (int ct = 0; ct < 2; ++ct) {
            int cbase = (cw * 2 + ct) * 32 + 4 * half;
#pragma unroll
            for (int g = 0; g < 4; ++g) {
                int co = cbase + 8 * g;
                if (co >= COUT) continue;
                float4 bv = *(const float4*)(bias + co);
#pragma unroll
                for (int lt = 0; lt < 2; ++lt) {
                    int l = l0 + lw * 64 + lt * 32 + ln31;
                    if (l < LP) {
                        ushort_t h0 = f2bf(fmaxf(acc[ct][lt][4 * g + 0] + bv.x, 0.f));
                        ushort_t h1 = f2bf(fmaxf(acc[ct][lt][4 * g + 1] + bv.y, 0.f));
                        ushort_t h2 = f2bf(fmaxf(acc[ct][lt][4 * g + 2] + bv.z, 0.f));
                        ushort_t h3 = f2bf(fmaxf(acc[ct][lt][4 * g + 3] + bv.w, 0.f));
                        uint2 o;
                        o.x = (unsigned)h0 | ((unsigned)h1 << 16);
                        o.y = (unsigned)h2 | ((unsigned)h3 << 16);
                        *(uint2*)(out + (size_t)l * COUT + co) = o;
                    }
                }
            }
        }
    } else {
        float* xout = (float*)outv;
#pragma unroll
        for (int ct = 0; ct < 2; ++ct) {
            float mx[16];
#pragma unroll
            for (int r = 0; r < 16; ++r) mx[r] = -3.0e38f;
#pragma unroll
            for (int lt = 0; lt < 2; ++lt) {
                int l = l0 + lw * 64 + lt * 32 + ln31;
                if (l < LP) {
#pragma unroll
                    for (int r = 0; r < 16; ++r) mx[r] = fmaxf(mx[r], acc[ct][lt][r]);
                }
            }
#pragma unroll
            for (int r = 0; r < 16; ++r) {
#pragma unroll
                for (int off = 1; off < 32; off <<= 1)
                    mx[r] = fmaxf(mx[r], __shfl_xor(mx[r], off, 64));
            }
            if (ln31 == 0) {
                int cbase = (cw * 2 + ct) * 32 + 4 * half;
#pragma unroll
                for (int r = 0; r < 16; ++r) {
                    int co = cbase + (r & 3) + 8 * (r >> 2);
                    if (co < COUT) {
                        float v = fmaxf(mx[r] + bias[co], 0.f);
                        atomicMax((int*)&xout[(size_t)b * 400 + 200 + co], __float_as_int(v));
                    }
                }
            }
        }
    }
}

// ---------------- msg update via MFMA GEMM (R10 WIN, unchanged) ----------------
#define MPITCH 216   // 208 + 8 ushorts
static __device__ __forceinline__ void msg_body(
        int blk, const float* __restrict__ msgIn, const float* __restrict__ binput,
        const int* __restrict__ bgraph, const ushort_t* __restrict__ Wbh,
        float* __restrict__ msgOut, ushort_t* __restrict__ Xs, int* __restrict__ idxs) {
    constexpr int D = 4;
    int m0 = blk * 32;
    int tid = threadIdx.x;

    if (tid < 192) {
        int r = tid / 6, j = tid - r * 6;
        int m = m0 + r;
        int mol = m / NBB;
        idxs[tid] = mol * NBB + bgraph[(size_t)m * 6 + j];
    }
    __syncthreads();

    for (int it = tid; it < 32 * 26; it += 256) {
        int r = it / 26, c = it - r * 26;
        uint4 v = {0u, 0u, 0u, 0u};
        if (c < 25) {
            float sv[8];
#pragma unroll
            for (int k = 0; k < 8; ++k) sv[k] = 0.f;
#pragma unroll
            for (int j = 0; j < 6; ++j) {
                const float* row = msgIn + (size_t)idxs[r * 6 + j] * H + c * 8;
                float4 a = *(const float4*)row;
                float4 b = *(const float4*)(row + 4);
                sv[0] += a.x; sv[1] += a.y; sv[2] += a.z; sv[3] += a.w;
                sv[4] += b.x; sv[5] += b.y; sv[6] += b.z; sv[7] += b.w;
            }
            v.x = (unsigned)f2bf(sv[0]) | ((unsigned)f2bf(sv[1]) << 16);
            v.y = (unsigned)f2bf(sv[2]) | ((unsigned)f2bf(sv[3]) << 16);
            v.z = (unsigned)f2bf(sv[4]) | ((unsigned)f2bf(sv[5]) << 16);
            v.w = (unsigned)f2bf(sv[6]) | ((unsigned)f2bf(sv[7]) << 16);
        }
        *(uint4*)(Xs + r * MPITCH + c * 8) = v;
    }

    int lane = tid & 63, wv = tid >> 6;
    int ln31 = lane & 31, half = lane >> 5;
    unsigned abase0 = (unsigned)(wv * 2) * (unsigned)MNS * 1024u + (unsigned)lane * 16u;
    unsigned abase1 = abase0 + (unsigned)MNS * 1024u;
    int bbase = ln31 * MPITCH + half * 8;

    f32x16 acc[2];
#pragma unroll
    for (int ct = 0; ct < 2; ++ct)
#pragma unroll
        for (int r = 0; r < 16; ++r) acc[ct][r] = 0.f;

    __syncthreads();

    uint32x4 ra0[4], ra1[4];
#pragma unroll
    for (int d = 0; d < D; ++d) {
        ra0[d] = gload16(Wbh, abase0 + (unsigned)(d * 1024));
        ra1[d] = gload16(Wbh, abase1 + (unsigned)(d * 1024));
    }

    uint4 bC = *(const uint4*)(Xs + bbase);

#pragma unroll
    for (int s = 0; s < MNS; ++s) {
        int sn = (s + 1 < MNS) ? s + 1 : MNS - 1;
        uint4 bN = *(const uint4*)(Xs + bbase + sn * 16);

        {
            const int rem = MNS - 1 - s;
            const int allow = 2 * ((D - 1) < rem ? (D - 1) : rem);
            asm volatile("s_waitcnt vmcnt(%0)" :: "i"(allow) : "memory");
            __builtin_amdgcn_sched_barrier(0);
        }

        uint32x4 a0 = ra0[s % D];
        uint32x4 a1 = ra1[s % D];
        acc[0] = __builtin_amdgcn_mfma_f32_32x32x16_bf16(
            as_bf16x8v(a0), as_bf16x8(bC), acc[0], 0, 0, 0);
        acc[1] = __builtin_amdgcn_mfma_f32_32x32x16_bf16(
            as_bf16x8v(a1), as_bf16x8(bC), acc[1], 0, 0, 0);

        if (s + D < MNS) {
            ra0[s % D] = gload16(Wbh, abase0 + (unsigned)((s + D) * 1024));
            ra1[s % D] = gload16(Wbh, abase1 + (unsigned)((s + D) * 1024));
        }
        bC = bN;
    }

    int m = m0 + ln31;
    const float* bi = binput + (size_t)m * H;
    float* outp = msgOut + (size_t)m * H;
#pragma unroll
    for (int ct = 0; ct < 2; ++ct) {
        int cbase = (wv * 2 + ct) * 32 + 4 * half;
#pragma unroll
        for (int g = 0; g < 4; ++g) {
            int co = cbase + 8 * g;
            if (co >= H) continue;
            float4 b4 = *(const float4*)(bi + co);
            float4 o;
            o.x = fmaxf(acc[ct][4 * g + 0] + b4.x, 0.f);
            o.y = fmaxf(acc[ct][4 * g + 1] + b4.y, 0.f);
            o.z = fmaxf(acc[ct][4 * g + 2] + b4.z, 0.f);
            o.w = fmaxf(acc[ct][4 * g + 3] + b4.w, 0.f);
            *(float4*)(outp + co) = o;
        }
    }
}

// ---------------- atom head via MFMA GEMM (R12 WIN, unchanged) ----------------
#define APITCH 248   // 240 + 8 ushorts
static __device__ __forceinline__ void atom_mfma_body(
        int blk, const float* __restrict__ msg, const float* __restrict__ fatoms,
        const int* __restrict__ agraph, const ushort_t* __restrict__ Wbo,
        const float* __restrict__ Wob, float* __restrict__ x,
        ushort_t* __restrict__ Xs, int* __restrict__ idxs) {
    constexpr int D = 4;
    int m0 = blk * 32;
    int tid = threadIdx.x;

    if (tid < 192) {
        int r = tid / 6, j = tid - r * 6;
        int m = m0 + r;
        int mol = m / NA;
        idxs[tid] = mol * NBB + agraph[(size_t)m * 6 + j];
    }
    __syncthreads();

    for (int it = tid; it < 32 * 30; it += 256) {
        int r = it / 30, c = it - r * 30;
        uint4 v = {0u, 0u, 0u, 0u};
        if (c < 25) {
            float sv[8];
#pragma unroll
            for (int k = 0; k < 8; ++k) sv[k] = 0.f;
#pragma unroll
            for (int j = 0; j < 6; ++j) {
                const float* row = msg + (size_t)idxs[r * 6 + j] * H + c * 8;
                float4 a = *(const float4*)row;
                float4 b = *(const float4*)(row + 4);
                sv[0] += a.x; sv[1] += a.y; sv[2] += a.z; sv[3] += a.w;
                sv[4] += b.x; sv[5] += b.y; sv[6] += b.z; sv[7] += b.w;
            }
            v.x = (unsigned)f2bf(sv[0]) | ((unsigned)f2bf(sv[1]) << 16);
            v.y = (unsigned)f2bf(sv[2]) | ((unsigned)f2bf(sv[3]) << 16);
            v.z = (unsigned)f2bf(sv[4]) | ((unsigned)f2bf(sv[5]) << 16);
            v.w = (unsigned)f2bf(sv[6]) | ((unsigned)f2bf(sv[7]) << 16);
        } else {
            int m = m0 + r;
            ushort_t h[8];
#pragma unroll
            for (int j = 0; j < 8; ++j) {
                int f = c * 8 + j - 200;
                h[j] = (f < AFD) ? f2bf(fatoms[(size_t)m * AFD + f]) : (ushort_t)0;
            }
            v.x = (unsigned)h[0] | ((unsigned)h[1] << 16);
            v.y = (unsigned)h[2] | ((unsigned)h[3] << 16);
            v.z = (unsigned)h[4] | ((unsigned)h[5] << 16);
            v.w = (unsigned)h[6] | ((unsigned)h[7] << 16);
        }
        *(uint4*)(Xs + r * APITCH + c * 8) = v;
    }

    int lane = tid & 63, wv = tid >> 6;
    int ln31 = lane & 31, half = lane >> 5;
    unsigned abase0 = (unsigned)(wv * 2) * (unsigned)ANS * 1024u + (unsigned)lane * 16u;
    unsigned abase1 = abase0 + (unsigned)ANS * 1024u;
    int bbase = ln31 * APITCH + half * 8;

    f32x16 acc[2];
#pragma unroll
    for (int ct = 0; ct < 2; ++ct)
#pragma unroll
        for (int r = 0; r < 16; ++r) acc[ct][r] = 0.f;

    __syncthreads();

    uint32x4 ra0[4], ra1[4];
#pragma unroll
    for (int d = 0; d < D; ++d) {
        ra0[d] = gload16(Wbo, abase0 + (unsigned)(d * 1024));
        ra1[d] = gload16(Wbo, abase1 + (unsigned)(d * 1024));
    }

    uint4 bC = *(const uint4*)(Xs + bbase);

#pragma unroll
    for (int s = 0; s < ANS; ++s) {
        int sn = (s + 1 < ANS) ? s + 1 : ANS - 1;
        uint4 bN = *(const uint4*)(Xs + bbase + sn * 16);

        {
            const int rem = ANS - 1 - s;
            const int allow = 2 * ((D - 1) < rem ? (D - 1) : rem);
            asm volatile("s_waitcnt vmcnt(%0)" :: "i"(allow) : "memory");
            __builtin_amdgcn_sched_barrier(0);
        }

        uint32x4 a0 = ra0[s % D];
        uint32x4 a1 = ra1[s % D];
        acc[0] = __builtin_amdgcn_mfma_f32_32x32x16_bf16(
            as_bf16x8v(a0), as_bf16x8(bC), acc[0], 0, 0, 0);
        acc[1] = __builtin_amdgcn_mfma_f32_32x32x16_bf16(
            as_bf16x8v(a1), as_bf16x8(bC), acc[1], 0, 0, 0);

        if (s + D < ANS) {
            ra0[s % D] = gload16(Wbo, abase0 + (unsigned)((s + D) * 1024));
            ra1[s % D] = gload16(Wbo, abase1 + (unsigned)((s + D) * 1024));
        }
        bC = bN;
    }

    int rm = m0 % 48;
    bool split = (rm == 32);
    int molA = m0 / 48;
    const float inv = 1.f / NA;
#pragma unroll
    for (int ct = 0; ct < 2; ++ct) {
        int cbase = (wv * 2 + ct) * 32 + 4 * half;
#pragma unroll
        for (int r = 0; r < 16; ++r) {
            int co = cbase + (r & 3) + 8 * (r >> 2);
            float v = 0.f;
            if (co < H) v = fmaxf(acc[ct][r] + Wob[co], 0.f) * inv;
            v += __shfl_xor(v, 1, 64);
            v += __shfl_xor(v, 2, 64);
            v += __shfl_xor(v, 4, 64);
            v += __shfl_xor(v, 8, 64);
            if (!split) v += __shfl_xor(v, 16, 64);
            if (co < H) {
                if (ln31 == 0) atomicAdd(&x[(size_t)molA * 400 + co], v);
                else if (split && ln31 == 16) atomicAdd(&x[(size_t)(molA + 1) * 400 + co], v);
            }
        }
    }
}

// ---------------- bond input body ----------------
static __device__ __forceinline__ void bond_body(
        int blk, const float* __restrict__ fbonds, const float* __restrict__ Wi,
        float* __restrict__ binput, float* __restrict__ msg, float (*fb)[BFD]) {
    int bond0 = blk * BIPB;
    int tid = threadIdx.x;
    for (int idx = tid; idx < BIPB * BFD; idx += 256)
        fb[idx / BFD][idx % BFD] = fbonds[(size_t)bond0 * BFD + idx];
    __syncthreads();
    if (tid < H) {
        float acc[BIPB];
#pragma unroll
        for (int q = 0; q < BIPB; ++q) acc[q] = 0.f;
#pragma unroll 5
        for (int k = 0; k < BFD; ++k) {
            float w = Wi[k * H + tid];
#pragma unroll
            for (int q = 0; q < BIPB; ++q) acc[q] += fb[q][k] * w;
        }
#pragma unroll
        for (int q = 0; q < BIPB; ++q) {
            size_t o = (size_t)(bond0 + q) * H + tid;
            binput[o] = acc[q];
            msg[o] = fmaxf(acc[q], 0.f);
        }
    }
}

// ================= launches =================
// L0: prep || bond.  L1: conv0 || msg1.  L2: conv1 || msg2.
// L3a/b: conv2 half-batches (R17 visibility: hidden kernels >36us surface).
// L3c: atom solo.  L4: fc.

__global__ __launch_bounds__(256) void k_l0_prep_bond(
        const float* __restrict__ c0w, const float* __restrict__ c1w,
        const float* __restrict__ c2w, const float* __restrict__ Wh,
        const float* __restrict__ Wo, const float* __restrict__ emb,
        const float* __restrict__ fc0w, const float* __restrict__ fc1w,
        float* __restrict__ x,
        ushort_t* __restrict__ Wb0, ushort_t* __restrict__ Wb1,
        ushort_t* __restrict__ Wb2, ushort_t* __restrict__ Wbh,
        ushort_t* __restrict__ Wbo, ushort_t* __restrict__ embb,
        float* __restrict__ w0t, float* __restrict__ w1t,
        const float* __restrict__ fbonds, const float* __restrict__ Wi,
        float* __restrict__ binput, float* __restrict__ msgA) {
    __shared__ float fb[BIPB][BFD];
    int bid = blockIdx.x;
    if (bid < PREP_BLKS) {
        prep_body(bid * 256 + threadIdx.x, c0w, c1w, c2w, Wh, Wo, emb, fc0w, fc1w, x,
                  Wb0, Wb1, Wb2, Wbh, Wbo, embb, w0t, w1t);
    } else {
        bond_body(bid - PREP_BLKS, fbonds, Wi, binput, msgA, fb);
    }
}

__global__ __launch_bounds__(256, 4) void k_l1_conv0_msg(
        const int* __restrict__ seq, const ushort_t* __restrict__ embb,
        const ushort_t* __restrict__ Wb0, const float* __restrict__ c0b,
        ushort_t* __restrict__ act1,
        const float* __restrict__ msgIn, const float* __restrict__ binput,
        const int* __restrict__ bgraph, const ushort_t* __restrict__ Wbh,
        float* __restrict__ msgOut) {
    __shared__ __align__(16) ushort_t Sbuf[(128 + 2) * (64 + 8)];  // 9360 ushorts
    if (blockIdx.x < 8) {
        conv_body<64, 3, 96, 2, 2, false, true>(nullptr, seq, embb, Wb0, c0b, act1, Sbuf, 0);
    } else {
        int blk = (blockIdx.x - 8) * 128 + blockIdx.z;   // 0..383
        msg_body(blk, msgIn, binput, bgraph, Wbh, msgOut, Sbuf,
                 (int*)(Sbuf + 32 * MPITCH));
    }
}

__global__ __launch_bounds__(256, 4) void k_l2_conv1_msg(
        const ushort_t* __restrict__ act1, const ushort_t* __restrict__ Wb1,
        const float* __restrict__ c1b, ushort_t* __restrict__ act2,
        const float* __restrict__ msgIn, const float* __restrict__ binput,
        const int* __restrict__ bgraph, const ushort_t* __restrict__ Wbh,
        float* __restrict__ msgOut) {
    __shared__ __align__(16) ushort_t Sbuf[(128 + 4) * (96 + 8)];  // 13728 ushorts
    if (blockIdx.x < 8) {
        conv_body<96, 5, 128, 2, 2, false, false>(act1, nullptr, nullptr, Wb1, c1b, act2,
                                                  Sbuf, 0);
    } else {
        int blk = (blockIdx.x - 8) * 128 + blockIdx.z;
        msg_body(blk, msgIn, binput, bgraph, Wbh, msgOut, Sbuf,
                 (int*)(Sbuf + 32 * MPITCH));
    }
}

__global__ __launch_bounds__(256, 4) void k_conv2a(
        const ushort_t* __restrict__ act2, const ushort_t* __restrict__ Wb2,
        const float* __restrict__ c2b, float* __restrict__ x) {
    __shared__ __align__(16) ushort_t Xs[(64 + 6) * (128 + 8)];
    conv_body<128, 7, 200, 4, 1, true, false>(act2, nullptr, nullptr, Wb2, c2b, x, Xs, 0);
}
__global__ __launch_bounds__(256, 4) void k_conv2b(
        const ushort_t* __restrict__ act2, const ushort_t* __restrict__ Wb2,
        const float* __restrict__ c2b, float* __restrict__ x) {
    __shared__ __align__(16) ushort_t Xs[(64 + 6) * (128 + 8)];
    conv_body<128, 7, 200, 4, 1, true, false>(act2, nullptr, nullptr, Wb2, c2b, x, Xs, 64);
}

__global__ __launch_bounds__(256, 4) void k_atom_mfma(
        const float* __restrict__ msg, const float* __restrict__ fatoms,
        const int* __restrict__ agraph, const ushort_t* __restrict__ Wbo,
        const float* __restrict__ Wob, float* __restrict__ x) {
    __shared__ __align__(16) ushort_t Xs[32 * APITCH];
    __shared__ int idxs[192];
    atom_mfma_body(blockIdx.x, msg, fatoms, agraph, Wbo, Wob, x, Xs, idxs);
}

// ---------------- FC head, wave-split-K (R15/R16) ----------------
__global__ __launch_bounds__(512) void k_fc(
        const float* __restrict__ x,
        const float* __restrict__ w0t, const float* __restrict__ b0,
        const float* __restrict__ w1t, const float* __restrict__ b1,
        const float* __restrict__ w2, const float* __restrict__ b2,
        float* __restrict__ out) {
    int b = blockIdx.x, tid = threadIdx.x;
    int lane = tid & 63, wv = tid >> 6;   // 8 waves
    __shared__ __align__(16) float xr[400];
    __shared__ __align__(16) float h1[200];
    __shared__ __align__(16) float h2[100];
    for (int i = tid; i < 400; i += 512) xr[i] = x[(size_t)b * 400 + i];
    __syncthreads();
    for (int o = 0; o < 25; ++o) {
        int co = wv * 25 + o;
        const float* wr = w0t + (size_t)co * 400;
        int k0 = lane * 4;
        float4 wa = *(const float4*)(wr + k0);
        float4 xa = *(const float4*)(xr + k0);
        float s = wa.x * xa.x + wa.y * xa.y + wa.z * xa.z + wa.w * xa.w;
        int k1 = 256 + lane * 4;
        if (k1 < 400) {
            float4 wb = *(const float4*)(wr + k1);
            float4 xb = *(const float4*)(xr + k1);
            s += wb.x * xb.x + wb.y * xb.y + wb.z * xb.z + wb.w * xb.w;
        }
#pragma unroll
        for (int off = 1; off < 64; off <<= 1) s += __shfl_xor(s, off, 64);
        if (lane == 0) h1[co] = fmaxf(s + b0[co], 0.f);
    }
    __syncthreads();
    if (wv < 4) {
        for (int o = 0; o < 25; ++o) {
            int co = wv * 25 + o;
            const float* wr = w1t + (size_t)co * 200;
            float s = 0.f;
            int k0 = lane * 4;
            if (k0 < 200) {
                float4 wa = *(const float4*)(wr + k0);
                float4 xa = *(const float4*)(h1 + k0);
                s = wa.x * xa.x + wa.y * xa.y + wa.z * xa.z + wa.w * xa.w;
            }
#pragma unroll
            for (int off = 1; off < 64; off <<= 1) s += __shfl_xor(s, off, 64);
            if (lane == 0) h2[co] = fmaxf(s + b1[co], 0.f);
        }
    }
    __syncthreads();
    if (wv == 0) {
        float s = 0.f;
        int k0 = lane * 4;
        if (k0 < 100) {
            float4 wa = *(const float4*)(w2 + k0);
            float4 xa = *(const float4*)(h2 + k0);
            s = wa.x * xa.x + wa.y * xa.y + wa.z * xa.z + wa.w * xa.w;
        }
#pragma unroll
        for (int off = 1; off < 64; off <<= 1) s += __shfl_xor(s, off, 64);
        if (lane == 0) out[b] = s + b2[0];
    }
}

extern "C" void kernel_launch(void* const* d_in, const int* in_sizes, int n_in,
                              void* d_out, int out_size, void* d_ws, size_t ws_size,
                              hipStream_t stream) {
    const float* fatoms = (const float*)d_in[0];
    const float* fbonds = (const float*)d_in[1];
    const int* agraph = (const int*)d_in[2];
    const int* bgraph = (const int*)d_in[3];
    const int* seq = (const int*)d_in[4];
    const float* Wi = (const float*)d_in[5];
    const float* Wh = (const float*)d_in[6];
    const float* Wo = (const float*)d_in[7];
    const float* Wob = (const float*)d_in[8];
    const float* embp = (const float*)d_in[9];
    const float* c0w = (const float*)d_in[10];
    const float* c0b = (const float*)d_in[11];
    const float* c1w = (const float*)d_in[12];
    const float* c1b = (const float*)d_in[13];
    const float* c2w = (const float*)d_in[14];
    const float* c2b = (const float*)d_in[15];
    const float* fc0w = (const float*)d_in[16];
    const float* fc0b = (const float*)d_in[17];
    const float* fc1w = (const float*)d_in[18];
    const float* fc1b = (const float*)d_in[19];
    const float* fc2w = (const float*)d_in[20];
    const float* fc2b = (const float*)d_in[21];

    float* ws = (float*)d_ws;
    float* binput = ws;                    // 2457600
    float* msgA = binput + 2457600;        // 2457600
    float* msgB = msgA + 2457600;          // 2457600
    float* x = msgB + 2457600;             // 51200
    ushort_t* u = (ushort_t*)(x + 51200);  // bf16 region
    ushort_t* act1 = u;                    // 128000*96  = 12288000
    ushort_t* act2 = act1 + 12288000;      // 128000*128 = 16384000
    ushort_t* Wb0 = act2 + 16384000;       // 4*12*512  = 24576
    ushort_t* Wb1 = Wb0 + 24576;           // 4*30*512  = 61440
    ushort_t* Wb2 = Wb1 + 61440;           // 8*56*512  = 229376
    ushort_t* Wbh = Wb2 + 229376;          // 8*13*512  = 53248
    ushort_t* Wbo = Wbh + 53248;           // 8*15*512  = 61440
    ushort_t* embb = Wbo + 61440;          // 26*56     = 1456
    float* w0t = (float*)(embb + 1456);    // 200*400 f32
    float* w1t = w0t + 200 * 400;          // 100*200 f32

    // L0: prep || bond_input
    k_l0_prep_bond<<<PREP_BLKS + BATCH * NBB / BIPB, 256, 0, stream>>>(
        c0w, c1w, c2w, Wh, Wo, embp, fc0w, fc1w, x, Wb0, Wb1, Wb2, Wbh, Wbo, embb,
        w0t, w1t, fbonds, Wi, binput, msgA);

    // L1: conv0 || msg pass 1 (msgA -> msgB)
    k_l1_conv0_msg<<<dim3(8 + 3, 1, BATCH), 256, 0, stream>>>(
        seq, embb, Wb0, c0b, act1, msgA, binput, bgraph, Wbh, msgB);

    // L2: conv1 || msg pass 2 (msgB -> msgA)
    k_l2_conv1_msg<<<dim3(8 + 3, 1, BATCH), 256, 0, stream>>>(
        act1, Wb1, c1b, act2, msgB, binput, bgraph, Wbh, msgA);

    // L3a/b: conv2 half-batches (visibility instrument; D=4 restored)
    k_conv2a<<<dim3(16, 1, 64), 256, 0, stream>>>(act2, Wb2, c2b, x);
    k_conv2b<<<dim3(16, 1, 64), 256, 0, stream>>>(act2, Wb2, c2b, x);

    // L3c: atom-MFMA solo (192 blocks)
    k_atom_mfma<<<BATCH * NA / 32, 256, 0, stream>>>(msgA, fatoms, agraph, Wbo, Wob, x);

    // L4: fc head
    k_fc<<<BATCH, 512, 0, stream>>>(x, w0t, fc0b, w1t, fc1b, fc2w, fc2b, (float*)d_out);
}

// Round 17
// 299.215 us; speedup vs baseline: 1.0877x; 1.0877x over previous
//
#include <hip/hip_runtime.h>
#include <hip/hip_bf16.h>
#include <cstddef>

#define H 200
#define NA 48
#define NBB 96
#define BATCH 128
#define AFD 39
#define BFD 50          // 39+11
#define LP 1000
#define CATD (AFD + H)  // 239
#define BIPB 16         // bonds per block in bond-input kernel
#define VOCAB 26
#define EROW 56         // padded bf16 emb row (50 -> 56 ushorts, 16B-aligned)

typedef unsigned short ushort_t;
typedef __bf16 bf16x8 __attribute__((ext_vector_type(8)));
typedef float f32x16 __attribute__((ext_vector_type(16)));
typedef unsigned uint32x4 __attribute__((ext_vector_type(4)));

union U16B { uint4 u; bf16x8 b; };
static __device__ __forceinline__ bf16x8 as_bf16x8(uint4 u) { U16B x; x.u = u; return x.b; }
union U16B2 { uint32x4 u; bf16x8 b; };
static __device__ __forceinline__ bf16x8 as_bf16x8v(uint32x4 u) { U16B2 x; x.u = u; return x.b; }

// float -> bf16 (RNE)
static __device__ __forceinline__ ushort_t f2bf(float f) {
    union { float f; unsigned u; } a; a.f = f;
    unsigned r = (a.u + 0x7FFFu + ((a.u >> 16) & 1u)) >> 16;
    return (ushort_t)r;
}

// raw asm global load: 16B at sgpr-base + 32-bit voffset. asm volatile pins issue
// order -> counted vmcnt discipline stays valid. "=&v" early-clobber.
static __device__ __forceinline__ uint32x4 gload16(const ushort_t* base, unsigned voff) {
    uint32x4 r;
    asm volatile("global_load_dwordx4 %0, %1, %2"
                 : "=&v"(r) : "v"(voff), "s"(base));
    return r;
}

// ---------------- prep: weight swizzles (32x32x16 A-frag order) ----------------
template <int COUT, int CIN, int CP, int K>
static __device__ __forceinline__ void prep_one(int t, const float* __restrict__ w,
                                                ushort_t* __restrict__ Wb) {
    constexpr int NC = CP / 16;
    constexpr int NS = K * NC;
    int j = t & 7;
    int lane = (t >> 3) & 63;
    int s = (t >> 9) % NS;
    int ct = (t >> 9) / NS;
    int co = ct * 32 + (lane & 31);
    int tt = s / NC, cc = s % NC;
    int ci = cc * 16 + ((lane >> 5) & 1) * 8 + j;
    float v = 0.f;
    if (co < COUT && ci < CIN) v = w[((size_t)co * CIN + ci) * K + tt];
    Wb[t] = f2bf(v);
}

#define MNS 13                            // K-steps for msg GEMM (208/16)
#define ANS 15                            // K-steps for atom GEMM (240/16)
#define PREP_T0 (4 * 12 * 512)            // conv0: 4 tiles x NS=12
#define PREP_T1 (PREP_T0 + 4 * 30 * 512)  // conv1: 4 tiles x NS=30
#define PREP_T2 (PREP_T1 + 8 * 56 * 512)  // conv2: 8 tiles x NS=56
#define PREP_T3 (PREP_T2 + 51200)         // zero x
#define PREP_T4 (PREP_T3 + 8 * MNS * 512) // Wh swizzle: 8 tiles x 13 steps
#define PREP_T5 (PREP_T4 + 8 * ANS * 512) // Wo swizzle (permuted K: nei|fa|pad)
#define PREP_T6 (PREP_T5 + VOCAB * EROW)  // emb -> bf16 padded table (2.8KB)
#define PREP_T7 (PREP_T6 + 200 * 400)     // fc0w transpose (coalesced reads)
#define PREP_T8 (PREP_T7 + 100 * 200)     // fc1w transpose
#define PREP_BLKS ((PREP_T8 + 255) / 256)

static __device__ __forceinline__ void prep_body(
        int tid, const float* __restrict__ c0w, const float* __restrict__ c1w,
        const float* __restrict__ c2w, const float* __restrict__ Wh,
        const float* __restrict__ Wo, const float* __restrict__ emb,
        const float* __restrict__ fc0w, const float* __restrict__ fc1w,
        float* __restrict__ x,
        ushort_t* __restrict__ Wb0, ushort_t* __restrict__ Wb1,
        ushort_t* __restrict__ Wb2, ushort_t* __restrict__ Wbh,
        ushort_t* __restrict__ Wbo, ushort_t* __restrict__ embb,
        float* __restrict__ w0t, float* __restrict__ w1t) {
    if (tid < PREP_T0) prep_one<96, 50, 64, 3>(tid, c0w, Wb0);
    else if (tid < PREP_T1) prep_one<128, 96, 96, 5>(tid - PREP_T0, c1w, Wb1);
    else if (tid < PREP_T2) prep_one<200, 128, 128, 7>(tid - PREP_T1, c2w, Wb2);
    else if (tid < PREP_T3) x[tid - PREP_T2] = 0.f;
    else if (tid < PREP_T4) {
        // Wh stored (in,out): value for (co, ci) = Wh[ci*200 + co]
        int t = tid - PREP_T3;
        int j = t & 7;
        int lane = (t >> 3) & 63;
        int s = (t >> 9) % MNS;
        int tile = (t >> 9) / MNS;
        int co = tile * 32 + (lane & 31);
        int ci = s * 16 + ((lane >> 5) & 1) * 8 + j;
        float v = 0.f;
        if (co < H && ci < H) v = Wh[ci * H + co];
        Wbh[t] = f2bf(v);
    } else if (tid < PREP_T5) {
        // Wo stored (in=239, out=200). Permuted K-axis ci' : [0,200)=nei -> Wo row 39+ci',
        // [200,239)=fa -> Wo row ci'-200, 239 = pad.
        int t = tid - PREP_T4;
        int j = t & 7;
        int lane = (t >> 3) & 63;
        int s = (t >> 9) % ANS;
        int tile = (t >> 9) / ANS;
        int co = tile * 32 + (lane & 31);
        int cip = s * 16 + ((lane >> 5) & 1) * 8 + j;
        float v = 0.f;
        if (co < H) {
            if (cip < 200) v = Wo[(size_t)(39 + cip) * H + co];
            else if (cip < CATD) v = Wo[(size_t)(cip - 200) * H + co];
        }
        Wbo[t] = f2bf(v);
    } else if (tid < PREP_T6) {
        // bf16 emb table, zero-padded 50->56 (conv0 staging: 7 uint4s per row)
        int t = tid - PREP_T5;
        int s = t / EROW, cc = t - s * EROW;
        embb[t] = (cc < 50) ? f2bf(emb[(size_t)s * 50 + cc]) : (ushort_t)0;
    } else if (tid < PREP_T7) {
        // consecutive tid -> consecutive READ addr (co fastest); scattered writes.
        int t = tid - PREP_T6;
        int co = t % 200, k = t / 200;
        w0t[(size_t)co * 400 + k] = fc0w[(size_t)k * 200 + co];
    } else if (tid < PREP_T8) {
        int t = tid - PREP_T7;
        int co = t % 100, k = t / 100;
        w1t[(size_t)co * 200 + k] = fc1w[(size_t)k * 100 + co];
    }
}

// ---------------- MFMA conv1d body, 32x32x16 ----------------
// R8 WIN: inline-asm A ring (D=4), counted s_waitcnt vmcnt + sched_barrier(0).
// R19: activations act1/act2 stored CHUNK-MAJOR: chunk = co/8, elem addr
// ((co>>3)*LP + l)*8 + (co&7). Epilogue: wave's 32 lanes (l consecutive) x two
// half-waves (co&7 in {0,4}) write a contiguous 512B run -> whole HBM lines dirty
// (R17 rocprof: old [l][co] 8B-scatter gave 2.3-2.5x write amplification,
// k_l2 WRITE 95-105MB vs 42.6 ideal). Staging reads chunk c as contiguous l-runs
// (block covers 130 consecutive l per chunk -> ~1x read). R18's LDS-roundtrip
// variant crashed; this keeps R17's store count, only remapping addresses.
template <int CP, int K, int COUT, int CO_WAVES, int L_WAVES, bool FMAX, bool EMB>
static __device__ __forceinline__ void conv_body(
        const ushort_t* __restrict__ act, const int* __restrict__ seq,
        const ushort_t* __restrict__ embb, const ushort_t* __restrict__ Wb,
        const float* __restrict__ bias, void* __restrict__ outv,
        ushort_t* __restrict__ Xs, int bofs) {
    constexpr int NC = CP / 16;
    constexpr int NS = K * NC;
    constexpr int P = K / 2;
    constexpr int PITCH = CP + 8;
    constexpr int LTILE = 64 * L_WAVES;
    constexpr int ROWS = LTILE + K - 1;
    constexpr int CPR = CP / 8;
    constexpr int D = 4;

    int b = blockIdx.z + bofs, lb = blockIdx.x;
    int l0 = lb * LTILE;
    int tid = threadIdx.x;

    if (EMB) {
        const int* seqb = seq + (size_t)b * LP;
        for (int idx = tid; idx < ROWS * CPR; idx += 256) {
            int r = idx / CPR, c = idx % CPR;
            int l = l0 - P + r;
            uint4 v = {0u, 0u, 0u, 0u};
            if ((unsigned)l < (unsigned)LP && c < 7) {
                int s = seqb[l];
                v = *(const uint4*)(embb + (size_t)s * EROW + c * 8);
            }
            *(uint4*)(Xs + r * PITCH + c * 8) = v;
        }
    } else {
        // chunk-major input: chunk c, row l at ((c*LP + l)*8)
        const ushort_t* actb = act + (size_t)b * LP * CP;
        for (int idx = tid; idx < ROWS * CPR; idx += 256) {
            int r = idx / CPR, c = idx % CPR;
            int l = l0 - P + r;
            uint4 v = {0u, 0u, 0u, 0u};
            if ((unsigned)l < (unsigned)LP)
                v = *(const uint4*)(actb + ((size_t)c * LP + l) * 8);
            *(uint4*)(Xs + r * PITCH + c * 8) = v;
        }
    }

    int lane = tid & 63, wv = tid >> 6;
    int cw = wv % CO_WAVES, lw = wv / CO_WAVES;
    int ln31 = lane & 31, half = lane >> 5;

    unsigned abase0 = (unsigned)(cw * 2) * (unsigned)NS * 1024u + (unsigned)lane * 16u;
    unsigned abase1 = abase0 + (unsigned)NS * 1024u;
    int bbase = (lw * 64 + ln31) * PITCH + half * 8;

    f32x16 acc[2][2];
#pragma unroll
    for (int ct = 0; ct < 2; ++ct)
#pragma unroll
        for (int lt = 0; lt < 2; ++lt)
#pragma unroll
            for (int r = 0; r < 16; ++r) acc[ct][lt][r] = 0.f;

    __syncthreads();   // staging drained -> vmcnt counts ONLY ring loads

    uint32x4 ra0[D], ra1[D];
#pragma unroll
    for (int d = 0; d < D; ++d) {
        ra0[d] = gload16(Wb, abase0 + (unsigned)(d * 1024));
        ra1[d] = gload16(Wb, abase1 + (unsigned)(d * 1024));
    }

    uint4 bC0 = *(const uint4*)(Xs + bbase);
    uint4 bC1 = *(const uint4*)(Xs + bbase + 32 * PITCH);

#pragma unroll
    for (int s = 0; s < NS; ++s) {
        int sn = (s + 1 < NS) ? s + 1 : NS - 1;
        int tn = sn / NC, ccn = sn % NC;
        int off = bbase + tn * PITCH + ccn * 16;
        uint4 bN0 = *(const uint4*)(Xs + off);
        uint4 bN1 = *(const uint4*)(Xs + off + 32 * PITCH);

        {
            const int rem = NS - 1 - s;
            const int allow = 2 * ((D - 1) < rem ? (D - 1) : rem);
            asm volatile("s_waitcnt vmcnt(%0)" :: "i"(allow) : "memory");
            __builtin_amdgcn_sched_barrier(0);
        }

        uint32x4 a0 = ra0[s % D];
        uint32x4 a1 = ra1[s % D];

        acc[0][0] = __builtin_amdgcn_mfma_f32_32x32x16_bf16(
            as_bf16x8v(a0), as_bf16x8(bC0), acc[0][0], 0, 0, 0);
        acc[1][0] = __builtin_amdgcn_mfma_f32_32x32x16_bf16(
            as_bf16x8v(a1), as_bf16x8(bC0), acc[1][0], 0, 0, 0);
        acc[0][1] = __builtin_amdgcn_mfma_f32_32x32x16_bf16(
            as_bf16x8v(a0), as_bf16x8(bC1), acc[0][1], 0, 0, 0);
        acc[1][1] = __builtin_amdgcn_mfma_f32_32x32x16_bf16(
            as_bf16x8v(a1), as_bf16x8(bC1), acc[1][1], 0, 0, 0);

        if (s + D < NS) {
            ra0[s % D] = gload16(Wb, abase0 + (unsigned)((s + D) * 1024));
            ra1[s % D] = gload16(Wb, abase1 + (unsigned)((s + D) * 1024));
        }

        bC0 = bN0; bC1 = bN1;
    }

    if (!FMAX) {
        // chunk-major coalesced store: uint2 at ((co>>3)*LP + l)*8 + (co&7).
        // lanes: l = ..+ln31 (stride 16B), half-waves cover co&7 = 0 / 4.
        ushort_t* out = (ushort_t*)outv + (size_t)b * LP * COUT;
#pragma unroll
        for (int ct = 0; ct < 2; ++ct) {
            int cbase = (cw * 2 + ct) * 32 + 4 * half;
#pragma unroll
            for (int g = 0; g < 4; ++g) {
                int co = cbase + 8 * g;
                if (co >= COUT) continue;
                float4 bv = *(const float4*)(bias + co);
                size_t chbase = (size_t)(co >> 3) * LP;
                int sub = co & 7;
#pragma unroll
                for (int lt = 0; lt < 2; ++lt) {
                    int l = l0 + lw * 64 + lt * 32 + ln31;
                    if (l < LP) {
                        ushort_t h0 = f2bf(fmaxf(acc[ct][lt][4 * g + 0] + bv.x, 0.f));
                        ushort_t h1 = f2bf(fmaxf(acc[ct][lt][4 * g + 1] + bv.y, 0.f));
                        ushort_t h2 = f2bf(fmaxf(acc[ct][lt][4 * g + 2] + bv.z, 0.f));
                        ushort_t h3 = f2bf(fmaxf(acc[ct][lt][4 * g + 3] + bv.w, 0.f));
                        uint2 o;
                        o.x = (unsigned)h0 | ((unsigned)h1 << 16);
                        o.y = (unsigned)h2 | ((unsigned)h3 << 16);
                        *(uint2*)(out + (chbase + l) * 8 + sub) = o;
                    }
                }
            }
        }
    } else {
        float* xout = (float*)outv;
#pragma unroll
        for (int ct = 0; ct < 2; ++ct) {
            float mx[16];
#pragma unroll
            for (int r = 0; r < 16; ++r) mx[r] = -3.0e38f;
#pragma unroll
            for (int lt = 0; lt < 2; ++lt) {
                int l = l0 + lw * 64 + lt * 32 + ln31;
                if (l < LP) {
#pragma unroll
                    for (int r = 0; r < 16; ++r) mx[r] = fmaxf(mx[r], acc[ct][lt][r]);
                }
            }
#pragma unroll
            for (int r = 0; r < 16; ++r) {
#pragma unroll
                for (int off = 1; off < 32; off <<= 1)
                    mx[r] = fmaxf(mx[r], __shfl_xor(mx[r], off, 64));
            }
            if (ln31 == 0) {
                int cbase = (cw * 2 + ct) * 32 + 4 * half;
#pragma unroll
                for (int r = 0; r < 16; ++r) {
                    int co = cbase + (r & 3) + 8 * (r >> 2);
                    if (co < COUT) {
                        float v = fmaxf(mx[r] + bias[co], 0.f);
                        atomicMax((int*)&xout[(size_t)b * 400 + 200 + co], __float_as_int(v));
                    }
                }
            }
        }
    }
}

// ---------------- msg update via MFMA GEMM (R10 WIN, unchanged) ----------------
#define MPITCH 216   // 208 + 8 ushorts
static __device__ __forceinline__ void msg_body(
        int blk, const float* __restrict__ msgIn, const float* __restrict__ binput,
        const int* __restrict__ bgraph, const ushort_t* __restrict__ Wbh,
        float* __restrict__ msgOut, ushort_t* __restrict__ Xs, int* __restrict__ idxs) {
    constexpr int D = 4;
    int m0 = blk * 32;
    int tid = threadIdx.x;

    if (tid < 192) {
        int r = tid / 6, j = tid - r * 6;
        int m = m0 + r;
        int mol = m / NBB;
        idxs[tid] = mol * NBB + bgraph[(size_t)m * 6 + j];
    }
    __syncthreads();

    for (int it = tid; it < 32 * 26; it += 256) {
        int r = it / 26, c = it - r * 26;
        uint4 v = {0u, 0u, 0u, 0u};
        if (c < 25) {
            float sv[8];
#pragma unroll
            for (int k = 0; k < 8; ++k) sv[k] = 0.f;
#pragma unroll
            for (int j = 0; j < 6; ++j) {
                const float* row = msgIn + (size_t)idxs[r * 6 + j] * H + c * 8;
                float4 a = *(const float4*)row;
                float4 b = *(const float4*)(row + 4);
                sv[0] += a.x; sv[1] += a.y; sv[2] += a.z; sv[3] += a.w;
                sv[4] += b.x; sv[5] += b.y; sv[6] += b.z; sv[7] += b.w;
            }
            v.x = (unsigned)f2bf(sv[0]) | ((unsigned)f2bf(sv[1]) << 16);
            v.y = (unsigned)f2bf(sv[2]) | ((unsigned)f2bf(sv[3]) << 16);
            v.z = (unsigned)f2bf(sv[4]) | ((unsigned)f2bf(sv[5]) << 16);
            v.w = (unsigned)f2bf(sv[6]) | ((unsigned)f2bf(sv[7]) << 16);
        }
        *(uint4*)(Xs + r * MPITCH + c * 8) = v;
    }

    int lane = tid & 63, wv = tid >> 6;
    int ln31 = lane & 31, half = lane >> 5;
    unsigned abase0 = (unsigned)(wv * 2) * (unsigned)MNS * 1024u + (unsigned)lane * 16u;
    unsigned abase1 = abase0 + (unsigned)MNS * 1024u;
    int bbase = ln31 * MPITCH + half * 8;

    f32x16 acc[2];
#pragma unroll
    for (int ct = 0; ct < 2; ++ct)
#pragma unroll
        for (int r = 0; r < 16; ++r) acc[ct][r] = 0.f;

    __syncthreads();

    uint32x4 ra0[4], ra1[4];
#pragma unroll
    for (int d = 0; d < D; ++d) {
        ra0[d] = gload16(Wbh, abase0 + (unsigned)(d * 1024));
        ra1[d] = gload16(Wbh, abase1 + (unsigned)(d * 1024));
    }

    uint4 bC = *(const uint4*)(Xs + bbase);

#pragma unroll
    for (int s = 0; s < MNS; ++s) {
        int sn = (s + 1 < MNS) ? s + 1 : MNS - 1;
        uint4 bN = *(const uint4*)(Xs + bbase + sn * 16);

        {
            const int rem = MNS - 1 - s;
            const int allow = 2 * ((D - 1) < rem ? (D - 1) : rem);
            asm volatile("s_waitcnt vmcnt(%0)" :: "i"(allow) : "memory");
            __builtin_amdgcn_sched_barrier(0);
        }

        uint32x4 a0 = ra0[s % D];
        uint32x4 a1 = ra1[s % D];
        acc[0] = __builtin_amdgcn_mfma_f32_32x32x16_bf16(
            as_bf16x8v(a0), as_bf16x8(bC), acc[0], 0, 0, 0);
        acc[1] = __builtin_amdgcn_mfma_f32_32x32x16_bf16(
            as_bf16x8v(a1), as_bf16x8(bC), acc[1], 0, 0, 0);

        if (s + D < MNS) {
            ra0[s % D] = gload16(Wbh, abase0 + (unsigned)((s + D) * 1024));
            ra1[s % D] = gload16(Wbh, abase1 + (unsigned)((s + D) * 1024));
        }
        bC = bN;
    }

    int m = m0 + ln31;
    const float* bi = binput + (size_t)m * H;
    float* outp = msgOut + (size_t)m * H;
#pragma unroll
    for (int ct = 0; ct < 2; ++ct) {
        int cbase = (wv * 2 + ct) * 32 + 4 * half;
#pragma unroll
        for (int g = 0; g < 4; ++g) {
            int co = cbase + 8 * g;
            if (co >= H) continue;
            float4 b4 = *(const float4*)(bi + co);
            float4 o;
            o.x = fmaxf(acc[ct][4 * g + 0] + b4.x, 0.f);
            o.y = fmaxf(acc[ct][4 * g + 1] + b4.y, 0.f);
            o.z = fmaxf(acc[ct][4 * g + 2] + b4.z, 0.f);
            o.w = fmaxf(acc[ct][4 * g + 3] + b4.w, 0.f);
            *(float4*)(outp + co) = o;
        }
    }
}

// ---------------- atom head via MFMA GEMM (R12 WIN, unchanged) ----------------
#define APITCH 248   // 240 + 8 ushorts
static __device__ __forceinline__ void atom_mfma_body(
        int blk, const float* __restrict__ msg, const float* __restrict__ fatoms,
        const int* __restrict__ agraph, const ushort_t* __restrict__ Wbo,
        const float* __restrict__ Wob, float* __restrict__ x,
        ushort_t* __restrict__ Xs, int* __restrict__ idxs) {
    constexpr int D = 4;
    int m0 = blk * 32;
    int tid = threadIdx.x;

    if (tid < 192) {
        int r = tid / 6, j = tid - r * 6;
        int m = m0 + r;
        int mol = m / NA;
        idxs[tid] = mol * NBB + agraph[(size_t)m * 6 + j];
    }
    __syncthreads();

    for (int it = tid; it < 32 * 30; it += 256) {
        int r = it / 30, c = it - r * 30;
        uint4 v = {0u, 0u, 0u, 0u};
        if (c < 25) {
            float sv[8];
#pragma unroll
            for (int k = 0; k < 8; ++k) sv[k] = 0.f;
#pragma unroll
            for (int j = 0; j < 6; ++j) {
                const float* row = msg + (size_t)idxs[r * 6 + j] * H + c * 8;
                float4 a = *(const float4*)row;
                float4 b = *(const float4*)(row + 4);
                sv[0] += a.x; sv[1] += a.y; sv[2] += a.z; sv[3] += a.w;
                sv[4] += b.x; sv[5] += b.y; sv[6] += b.z; sv[7] += b.w;
            }
            v.x = (unsigned)f2bf(sv[0]) | ((unsigned)f2bf(sv[1]) << 16);
            v.y = (unsigned)f2bf(sv[2]) | ((unsigned)f2bf(sv[3]) << 16);
            v.z = (unsigned)f2bf(sv[4]) | ((unsigned)f2bf(sv[5]) << 16);
            v.w = (unsigned)f2bf(sv[6]) | ((unsigned)f2bf(sv[7]) << 16);
        } else {
            int m = m0 + r;
            ushort_t h[8];
#pragma unroll
            for (int j = 0; j < 8; ++j) {
                int f = c * 8 + j - 200;
                h[j] = (f < AFD) ? f2bf(fatoms[(size_t)m * AFD + f]) : (ushort_t)0;
            }
            v.x = (unsigned)h[0] | ((unsigned)h[1] << 16);
            v.y = (unsigned)h[2] | ((unsigned)h[3] << 16);
            v.z = (unsigned)h[4] | ((unsigned)h[5] << 16);
            v.w = (unsigned)h[6] | ((unsigned)h[7] << 16);
        }
        *(uint4*)(Xs + r * APITCH + c * 8) = v;
    }

    int lane = tid & 63, wv = tid >> 6;
    int ln31 = lane & 31, half = lane >> 5;
    unsigned abase0 = (unsigned)(wv * 2) * (unsigned)ANS * 1024u + (unsigned)lane * 16u;
    unsigned abase1 = abase0 + (unsigned)ANS * 1024u;
    int bbase = ln31 * APITCH + half * 8;

    f32x16 acc[2];
#pragma unroll
    for (int ct = 0; ct < 2; ++ct)
#pragma unroll
        for (int r = 0; r < 16; ++r) acc[ct][r] = 0.f;

    __syncthreads();

    uint32x4 ra0[4], ra1[4];
#pragma unroll
    for (int d = 0; d < D; ++d) {
        ra0[d] = gload16(Wbo, abase0 + (unsigned)(d * 1024));
        ra1[d] = gload16(Wbo, abase1 + (unsigned)(d * 1024));
    }

    uint4 bC = *(const uint4*)(Xs + bbase);

#pragma unroll
    for (int s = 0; s < ANS; ++s) {
        int sn = (s + 1 < ANS) ? s + 1 : ANS - 1;
        uint4 bN = *(const uint4*)(Xs + bbase + sn * 16);

        {
            const int rem = ANS - 1 - s;
            const int allow = 2 * ((D - 1) < rem ? (D - 1) : rem);
            asm volatile("s_waitcnt vmcnt(%0)" :: "i"(allow) : "memory");
            __builtin_amdgcn_sched_barrier(0);
        }

        uint32x4 a0 = ra0[s % D];
        uint32x4 a1 = ra1[s % D];
        acc[0] = __builtin_amdgcn_mfma_f32_32x32x16_bf16(
            as_bf16x8v(a0), as_bf16x8(bC), acc[0], 0, 0, 0);
        acc[1] = __builtin_amdgcn_mfma_f32_32x32x16_bf16(
            as_bf16x8v(a1), as_bf16x8(bC), acc[1], 0, 0, 0);

        if (s + D < ANS) {
            ra0[s % D] = gload16(Wbo, abase0 + (unsigned)((s + D) * 1024));
            ra1[s % D] = gload16(Wbo, abase1 + (unsigned)((s + D) * 1024));
        }
        bC = bN;
    }

    int rm = m0 % 48;
    bool split = (rm == 32);
    int molA = m0 / 48;
    const float inv = 1.f / NA;
#pragma unroll
    for (int ct = 0; ct < 2; ++ct) {
        int cbase = (wv * 2 + ct) * 32 + 4 * half;
#pragma unroll
        for (int r = 0; r < 16; ++r) {
            int co = cbase + (r & 3) + 8 * (r >> 2);
            float v = 0.f;
            if (co < H) v = fmaxf(acc[ct][r] + Wob[co], 0.f) * inv;
            v += __shfl_xor(v, 1, 64);
            v += __shfl_xor(v, 2, 64);
            v += __shfl_xor(v, 4, 64);
            v += __shfl_xor(v, 8, 64);
            if (!split) v += __shfl_xor(v, 16, 64);
            if (co < H) {
                if (ln31 == 0) atomicAdd(&x[(size_t)molA * 400 + co], v);
                else if (split && ln31 == 16) atomicAdd(&x[(size_t)(molA + 1) * 400 + co], v);
            }
        }
    }
}

// ---------------- bond input body ----------------
static __device__ __forceinline__ void bond_body(
        int blk, const float* __restrict__ fbonds, const float* __restrict__ Wi,
        float* __restrict__ binput, float* __restrict__ msg, float (*fb)[BFD]) {
    int bond0 = blk * BIPB;
    int tid = threadIdx.x;
    for (int idx = tid; idx < BIPB * BFD; idx += 256)
        fb[idx / BFD][idx % BFD] = fbonds[(size_t)bond0 * BFD + idx];
    __syncthreads();
    if (tid < H) {
        float acc[BIPB];
#pragma unroll
        for (int q = 0; q < BIPB; ++q) acc[q] = 0.f;
#pragma unroll 5
        for (int k = 0; k < BFD; ++k) {
            float w = Wi[k * H + tid];
#pragma unroll
            for (int q = 0; q < BIPB; ++q) acc[q] += fb[q][k] * w;
        }
#pragma unroll
        for (int q = 0; q < BIPB; ++q) {
            size_t o = (size_t)(bond0 + q) * H + tid;
            binput[o] = acc[q];
            msg[o] = fmaxf(acc[q], 0.f);
        }
    }
}

// ================= launches =================
// L0: prep || bond.  L1: conv0 || msg1.  L2: conv1 || msg2.
// L3: conv2 solo.  L3c: atom solo.  L4: fc.

__global__ __launch_bounds__(256) void k_l0_prep_bond(
        const float* __restrict__ c0w, const float* __restrict__ c1w,
        const float* __restrict__ c2w, const float* __restrict__ Wh,
        const float* __restrict__ Wo, const float* __restrict__ emb,
        const float* __restrict__ fc0w, const float* __restrict__ fc1w,
        float* __restrict__ x,
        ushort_t* __restrict__ Wb0, ushort_t* __restrict__ Wb1,
        ushort_t* __restrict__ Wb2, ushort_t* __restrict__ Wbh,
        ushort_t* __restrict__ Wbo, ushort_t* __restrict__ embb,
        float* __restrict__ w0t, float* __restrict__ w1t,
        const float* __restrict__ fbonds, const float* __restrict__ Wi,
        float* __restrict__ binput, float* __restrict__ msgA) {
    __shared__ float fb[BIPB][BFD];
    int bid = blockIdx.x;
    if (bid < PREP_BLKS) {
        prep_body(bid * 256 + threadIdx.x, c0w, c1w, c2w, Wh, Wo, emb, fc0w, fc1w, x,
                  Wb0, Wb1, Wb2, Wbh, Wbo, embb, w0t, w1t);
    } else {
        bond_body(bid - PREP_BLKS, fbonds, Wi, binput, msgA, fb);
    }
}

__global__ __launch_bounds__(256, 4) void k_l1_conv0_msg(
        const int* __restrict__ seq, const ushort_t* __restrict__ embb,
        const ushort_t* __restrict__ Wb0, const float* __restrict__ c0b,
        ushort_t* __restrict__ act1,
        const float* __restrict__ msgIn, const float* __restrict__ binput,
        const int* __restrict__ bgraph, const ushort_t* __restrict__ Wbh,
        float* __restrict__ msgOut) {
    __shared__ __align__(16) ushort_t Sbuf[(128 + 2) * (64 + 8)];  // 9360 ushorts
    if (blockIdx.x < 8) {
        conv_body<64, 3, 96, 2, 2, false, true>(nullptr, seq, embb, Wb0, c0b, act1, Sbuf, 0);
    } else {
        int blk = (blockIdx.x - 8) * 128 + blockIdx.z;   // 0..383
        msg_body(blk, msgIn, binput, bgraph, Wbh, msgOut, Sbuf,
                 (int*)(Sbuf + 32 * MPITCH));
    }
}

__global__ __launch_bounds__(256, 4) void k_l2_conv1_msg(
        const ushort_t* __restrict__ act1, const ushort_t* __restrict__ Wb1,
        const float* __restrict__ c1b, ushort_t* __restrict__ act2,
        const float* __restrict__ msgIn, const float* __restrict__ binput,
        const int* __restrict__ bgraph, const ushort_t* __restrict__ Wbh,
        float* __restrict__ msgOut) {
    __shared__ __align__(16) ushort_t Sbuf[(128 + 4) * (96 + 8)];  // 13728 ushorts
    if (blockIdx.x < 8) {
        conv_body<96, 5, 128, 2, 2, false, false>(act1, nullptr, nullptr, Wb1, c1b, act2,
                                                  Sbuf, 0);
    } else {
        int blk = (blockIdx.x - 8) * 128 + blockIdx.z;
        msg_body(blk, msgIn, binput, bgraph, Wbh, msgOut, Sbuf,
                 (int*)(Sbuf + 32 * MPITCH));
    }
}

__global__ __launch_bounds__(256, 4) void k_conv2(
        const ushort_t* __restrict__ act2, const ushort_t* __restrict__ Wb2,
        const float* __restrict__ c2b, float* __restrict__ x) {
    __shared__ __align__(16) ushort_t Xs[(64 + 6) * (128 + 8)];
    conv_body<128, 7, 200, 4, 1, true, false>(act2, nullptr, nullptr, Wb2, c2b, x, Xs, 0);
}

__global__ __launch_bounds__(256, 4) void k_atom_mfma(
        const float* __restrict__ msg, const float* __restrict__ fatoms,
        const int* __restrict__ agraph, const ushort_t* __restrict__ Wbo,
        const float* __restrict__ Wob, float* __restrict__ x) {
    __shared__ __align__(16) ushort_t Xs[32 * APITCH];
    __shared__ int idxs[192];
    atom_mfma_body(blockIdx.x, msg, fatoms, agraph, Wbo, Wob, x, Xs, idxs);
}

// ---------------- FC head, wave-split-K (R15/R16) ----------------
__global__ __launch_bounds__(512) void k_fc(
        const float* __restrict__ x,
        const float* __restrict__ w0t, const float* __restrict__ b0,
        const float* __restrict__ w1t, const float* __restrict__ b1,
        const float* __restrict__ w2, const float* __restrict__ b2,
        float* __restrict__ out) {
    int b = blockIdx.x, tid = threadIdx.x;
    int lane = tid & 63, wv = tid >> 6;   // 8 waves
    __shared__ __align__(16) float xr[400];
    __shared__ __align__(16) float h1[200];
    __shared__ __align__(16) float h2[100];
    for (int i = tid; i < 400; i += 512) xr[i] = x[(size_t)b * 400 + i];
    __syncthreads();
    for (int o = 0; o < 25; ++o) {
        int co = wv * 25 + o;
        const float* wr = w0t + (size_t)co * 400;
        int k0 = lane * 4;
        float4 wa = *(const float4*)(wr + k0);
        float4 xa = *(const float4*)(xr + k0);
        float s = wa.x * xa.x + wa.y * xa.y + wa.z * xa.z + wa.w * xa.w;
        int k1 = 256 + lane * 4;
        if (k1 < 400) {
            float4 wb = *(const float4*)(wr + k1);
            float4 xb = *(const float4*)(xr + k1);
            s += wb.x * xb.x + wb.y * xb.y + wb.z * xb.z + wb.w * xb.w;
        }
#pragma unroll
        for (int off = 1; off < 64; off <<= 1) s += __shfl_xor(s, off, 64);
        if (lane == 0) h1[co] = fmaxf(s + b0[co], 0.f);
    }
    __syncthreads();
    if (wv < 4) {
        for (int o = 0; o < 25; ++o) {
            int co = wv * 25 + o;
            const float* wr = w1t + (size_t)co * 200;
            float s = 0.f;
            int k0 = lane * 4;
            if (k0 < 200) {
                float4 wa = *(const float4*)(wr + k0);
                float4 xa = *(const float4*)(h1 + k0);
                s = wa.x * xa.x + wa.y * xa.y + wa.z * xa.z + wa.w * xa.w;
            }
#pragma unroll
            for (int off = 1; off < 64; off <<= 1) s += __shfl_xor(s, off, 64);
            if (lane == 0) h2[co] = fmaxf(s + b1[co], 0.f);
        }
    }
    __syncthreads();
    if (wv == 0) {
        float s = 0.f;
        int k0 = lane * 4;
        if (k0 < 100) {
            float4 wa = *(const float4*)(w2 + k0);
            float4 xa = *(const float4*)(h2 + k0);
            s = wa.x * xa.x + wa.y * xa.y + wa.z * xa.z + wa.w * xa.w;
        }
#pragma unroll
        for (int off = 1; off < 64; off <<= 1) s += __shfl_xor(s, off, 64);
        if (lane == 0) out[b] = s + b2[0];
    }
}

extern "C" void kernel_launch(void* const* d_in, const int* in_sizes, int n_in,
                              void* d_out, int out_size, void* d_ws, size_t ws_size,
                              hipStream_t stream) {
    const float* fatoms = (const float*)d_in[0];
    const float* fbonds = (const float*)d_in[1];
    const int* agraph = (const int*)d_in[2];
    const int* bgraph = (const int*)d_in[3];
    const int* seq = (const int*)d_in[4];
    const float* Wi = (const float*)d_in[5];
    const float* Wh = (const float*)d_in[6];
    const float* Wo = (const float*)d_in[7];
    const float* Wob = (const float*)d_in[8];
    const float* embp = (const float*)d_in[9];
    const float* c0w = (const float*)d_in[10];
    const float* c0b = (const float*)d_in[11];
    const float* c1w = (const float*)d_in[12];
    const float* c1b = (const float*)d_in[13];
    const float* c2w = (const float*)d_in[14];
    const float* c2b = (const float*)d_in[15];
    const float* fc0w = (const float*)d_in[16];
    const float* fc0b = (const float*)d_in[17];
    const float* fc1w = (const float*)d_in[18];
    const float* fc1b = (const float*)d_in[19];
    const float* fc2w = (const float*)d_in[20];
    const float* fc2b = (const float*)d_in[21];

    float* ws = (float*)d_ws;
    float* binput = ws;                    // 2457600
    float* msgA = binput + 2457600;        // 2457600
    float* msgB = msgA + 2457600;          // 2457600
    float* x = msgB + 2457600;             // 51200
    ushort_t* u = (ushort_t*)(x + 51200);  // bf16 region
    ushort_t* act1 = u;                    // 128000*96  = 12288000 (chunk-major)
    ushort_t* act2 = act1 + 12288000;      // 128000*128 = 16384000 (chunk-major)
    ushort_t* Wb0 = act2 + 16384000;       // 4*12*512  = 24576
    ushort_t* Wb1 = Wb0 + 24576;           // 4*30*512  = 61440
    ushort_t* Wb2 = Wb1 + 61440;           // 8*56*512  = 229376
    ushort_t* Wbh = Wb2 + 229376;          // 8*13*512  = 53248
    ushort_t* Wbo = Wbh + 53248;           // 8*15*512  = 61440
    ushort_t* embb = Wbo + 61440;          // 26*56     = 1456
    float* w0t = (float*)(embb + 1456);    // 200*400 f32
    float* w1t = w0t + 200 * 400;          // 100*200 f32

    // L0: prep || bond_input
    k_l0_prep_bond<<<PREP_BLKS + BATCH * NBB / BIPB, 256, 0, stream>>>(
        c0w, c1w, c2w, Wh, Wo, embp, fc0w, fc1w, x, Wb0, Wb1, Wb2, Wbh, Wbo, embb,
        w0t, w1t, fbonds, Wi, binput, msgA);

    // L1: conv0 || msg pass 1 (msgA -> msgB)
    k_l1_conv0_msg<<<dim3(8 + 3, 1, BATCH), 256, 0, stream>>>(
        seq, embb, Wb0, c0b, act1, msgA, binput, bgraph, Wbh, msgB);

    // L2: conv1 || msg pass 2 (msgB -> msgA)
    k_l2_conv1_msg<<<dim3(8 + 3, 1, BATCH), 256, 0, stream>>>(
        act1, Wb1, c1b, act2, msgB, binput, bgraph, Wbh, msgA);

    // L3: conv2 solo
    k_conv2<<<dim3(16, 1, BATCH), 256, 0, stream>>>(act2, Wb2, c2b, x);

    // L3c: atom-MFMA solo (192 blocks)
    k_atom_mfma<<<BATCH * NA / 32, 256, 0, stream>>>(msgA, fatoms, agraph, Wbo, Wob, x);

    // L4: fc head
    k_fc<<<BATCH, 512, 0, stream>>>(x, w0t, fc0b, w1t, fc1b, fc2w, fc2b, (float*)d_out);
}